// Round 16
// baseline (514.309 us; speedup 1.0000x reference)
//
#include <hip/hip_runtime.h>

// Fused StyleGAN2 conv_downsample_2d, f32, register-FIR + SGPR-w GEMM,
// 4-wave blocks / 64-oc waves for finer residency + smaller barrier groups.
//   out[n,oc,oh,ow] = sum_c w[c,oc] * y[n,c,2oh,2ow]
//   y = separable FIR {1,3,3,1}/8 (vert) x {1,3,3,1}/8 (horiz), pad=1
//
// Design ledger (r1-r14):
//  - bf16 MFMA: precision-independent ~0.7 absmax on this op -> f32 VALU.
//  - NEVER pass __launch_bounds__ min-waves arg (r6/r8 spilled).
//  - r13 2-deep manual pipeline: +VALU, slower. Keep 1-deep prefetch.
//  - r14 b64 LDS reads: no effect -> LDS instr count not binding.
//  - Plateau diagnosis: stall-bound at per-chunk barrier convergence of
//    8-wave groups (only ~2 resident, breathing in lockstep). This round:
//    4-wave barrier groups, wave = 64 oc, acc[64]; VGPR ~120 -> up to 4
//    independent groups/CU; 2x FMA per barrier per thread.
//
// Block 256 thr = 4 waves. Tile: 256 oc x (4 oh x 16 ow). Wave wv: oc strip
// [wv*64, wv*64+64), stages chunk-channels {2wv, 2wv+1}. 16 chunks of 8 ch.
// Lanes 0..33 own patch columns (10 rows x 34 cols), vertical FIR in regs.

#define VS 35   // v_s col pitch (odd; measured 0 bank conflicts in r12)

__global__ __launch_bounds__(256)
void fused_downconv_v10(const float* __restrict__ x, const float* __restrict__ w,
                        float* __restrict__ out) {
    __shared__ __align__(16) float v_s[2 * 8 * 4 * VS];   // 8960 B

    const int tid  = threadIdx.x;
    const int lane = tid & 63;
    const int wv   = tid >> 6;   // wave id 0..3
    const int oc0  = __builtin_amdgcn_readfirstlane((tid >> 6) << 6);  // 64-oc strip
    const int cha  = 2 * wv;     // staged channels within chunk
    const int chb  = 2 * wv + 1;

    const int ow0 = blockIdx.x * 16;
    const int oh0 = blockIdx.y * 4;
    const int n   = blockIdx.z;

    const int rbase = 2 * oh0 - 1;
    const int cbase = 2 * ow0 - 1;

    // ---- staging map: lane<34 owns col cbase+lane, rows rbase..rbase+9 ----
    int off[10];
    unsigned ldmask = 0;
    {
        int gc = cbase + lane;
        bool cok = (lane < 34) && ((unsigned)gc < 512u);
        #pragma unroll
        for (int k = 0; k < 10; k++) {
            int gr = rbase + k;
            bool ok = cok && ((unsigned)gr < 512u);
            off[k] = ok ? (gr * 512 + gc) : 0;
            if (ok) ldmask |= 1u << k;
        }
    }

    const int owl = lane & 15;   // GEMM spatial mapping: lane = sp
    const int ohl = lane >> 4;

    float xrA[10], xrB[10];
    float acc[64];
    #pragma unroll
    for (int i = 0; i < 64; i++) acc[i] = 0.f;

    auto prefetch = [&](int c0) {
        const float* xa = x + ((size_t)(n * 128 + c0 + cha)) * 262144;
        const float* xb = x + ((size_t)(n * 128 + c0 + chb)) * 262144;
        #pragma unroll
        for (int k = 0; k < 10; k++) {
            xrA[k] = ((ldmask >> k) & 1u) ? xa[off[k]] : 0.f;
            xrB[k] = ((ldmask >> k) & 1u) ? xb[off[k]] : 0.f;
        }
    };
    auto vwrite = [&](int buf) {
        if (lane < 34) {
            #pragma unroll
            for (int o = 0; o < 4; o++) {
                float va = 0.125f * (xrA[2 * o] + xrA[2 * o + 3])
                         + 0.375f * (xrA[2 * o + 1] + xrA[2 * o + 2]);
                float vb = 0.125f * (xrB[2 * o] + xrB[2 * o + 3])
                         + 0.375f * (xrB[2 * o + 1] + xrB[2 * o + 2]);
                v_s[((buf * 8 + cha) * 4 + o) * VS + lane] = va;
                v_s[((buf * 8 + chb) * 4 + o) * VS + lane] = vb;
            }
        }
    };

    prefetch(0);
    vwrite(0);
    prefetch(8);
    __syncthreads();

    for (int t = 0; t < 16; t++) {
        const int buf = t & 1;
        if (t < 15) {
            vwrite(buf ^ 1);                   // chunk t+1 -> other buffer
            if (t < 14) prefetch((t + 2) * 8); // issue loads for chunk t+2
        }
        // ---- GEMM over the 8 channels of chunk t: 64 oc per thread ----
        #pragma unroll
        for (int cc = 0; cc < 8; cc++) {
            const float* vp = &v_s[((buf * 8 + cc) * 4 + ohl) * VS + 2 * owl];
            float v0 = vp[0], v1 = vp[1], v2 = vp[2], v3 = vp[3];
            float y = 0.125f * (v0 + v3) + 0.375f * (v1 + v2);
            const float* wrow = w + ((t * 8 + cc) << 8) + oc0;  // wave-uniform -> s_load
            #pragma unroll
            for (int i = 0; i < 64; i++)
                acc[i] = fmaf(wrow[i], y, acc[i]);
        }
        __syncthreads();   // v-writes(t+1) visible; GEMM(t) reads drained
    }

    // ---- epilogue: oc = oc0+i, oh = oh0+ohl, ow = ow0+owl ----
    {
        size_t base = (((size_t)n * 256 + oc0) * 256 + (size_t)(oh0 + ohl)) * 256
                      + ow0 + owl;
        #pragma unroll
        for (int i = 0; i < 64; i++)
            out[base + (size_t)i * 65536] = acc[i];
    }
}

extern "C" void kernel_launch(void* const* d_in, const int* in_sizes, int n_in,
                              void* d_out, int out_size, void* d_ws, size_t ws_size,
                              hipStream_t stream) {
    const float* x = (const float*)d_in[0];
    const float* w = (const float*)d_in[1];
    float* out = (float*)d_out;

    dim3 grid(16, 64, 4);   // ow-tiles(16 wide), oh-tiles(4 tall), n
    dim3 block(256);
    hipLaunchKernelGGL(fused_downconv_v10, grid, block, 0, stream, x, w, out);
}

// Round 17
// 422.556 us; speedup vs baseline: 1.2171x; 1.2171x over previous
//
#include <hip/hip_runtime.h>

// Fused StyleGAN2 conv_downsample_2d, f32, register-FIR + SGPR-w GEMM.
// r12 skeleton, ONE variable changed: CH 8 -> 16 (half the barriers, double
// the per-barrier GEMM run, 2x prefetch->use distance).
//   out[n,oc,oh,ow] = sum_c w[c,oc] * y[n,c,2oh,2ow]
//   y = separable FIR {1,3,3,1}/8 (vert) x {1,3,3,1}/8 (horiz), pad=1
//
// Design ledger (r1-r16):
//  - bf16 MFMA: precision-independent ~0.7 absmax (r2/3/5) -> f32 VALU.
//  - NEVER pass __launch_bounds__ min-waves arg (r6/r8 spilled).
//  - r13 manual 2-deep pipeline: +VALU, slower. r14 b64 LDS reads: null
//    (LDS instr count not binding). r16 4-wave/64-oc: slower (heavier waves).
//  - Stall structure: 16 barriers/block x (drain + skew) with ~2 resident
//    barrier groups; prefetch->use 550cyc < 900cyc HBM latency. This round
//    halves barrier count and doubles both the FMA run and prefetch distance.
//
// Block 512 thr = 8 waves. Tile: 256 oc x (4 oh x 16 ow). Wave wv: oc strip
// [wv*32, wv*32+32), stages channels {2wv, 2wv+1} of each 16-ch chunk.
// Lanes 0..33 own patch columns (10 rows x 34 cols), vertical FIR in regs.

#define VS 35   // v_s col pitch (odd; 0 bank conflicts measured r12/r14)

__global__ __launch_bounds__(512)
void fused_downconv_v11(const float* __restrict__ x, const float* __restrict__ w,
                        float* __restrict__ out) {
    __shared__ __align__(16) float v_s[2 * 16 * 4 * VS];   // 17920 B

    const int tid  = threadIdx.x;
    const int lane = tid & 63;
    const int wv   = tid >> 6;   // wave id 0..7
    const int oc0  = __builtin_amdgcn_readfirstlane((tid >> 6) << 5);  // 32-oc strip
    const int cha  = 2 * wv;     // staged channels within 16-chunk
    const int chb  = 2 * wv + 1;

    const int ow0 = blockIdx.x * 16;
    const int oh0 = blockIdx.y * 4;
    const int n   = blockIdx.z;

    const int rbase = 2 * oh0 - 1;
    const int cbase = 2 * ow0 - 1;

    // ---- staging map: lane<34 owns col cbase+lane, rows rbase..rbase+9 ----
    int off[10];
    unsigned ldmask = 0;
    {
        int gc = cbase + lane;
        bool cok = (lane < 34) && ((unsigned)gc < 512u);
        #pragma unroll
        for (int k = 0; k < 10; k++) {
            int gr = rbase + k;
            bool ok = cok && ((unsigned)gr < 512u);
            off[k] = ok ? (gr * 512 + gc) : 0;
            if (ok) ldmask |= 1u << k;
        }
    }

    const int owl = lane & 15;   // GEMM spatial mapping: lane = sp
    const int ohl = lane >> 4;

    float xrA[10], xrB[10];
    float acc[32];
    #pragma unroll
    for (int i = 0; i < 32; i++) acc[i] = 0.f;

    auto prefetch = [&](int c0) {
        const float* xa = x + ((size_t)(n * 128 + c0 + cha)) * 262144;
        const float* xb = x + ((size_t)(n * 128 + c0 + chb)) * 262144;
        #pragma unroll
        for (int k = 0; k < 10; k++) {
            xrA[k] = ((ldmask >> k) & 1u) ? xa[off[k]] : 0.f;
            xrB[k] = ((ldmask >> k) & 1u) ? xb[off[k]] : 0.f;
        }
    };
    auto vwrite = [&](int buf) {
        if (lane < 34) {
            #pragma unroll
            for (int o = 0; o < 4; o++) {
                float va = 0.125f * (xrA[2 * o] + xrA[2 * o + 3])
                         + 0.375f * (xrA[2 * o + 1] + xrA[2 * o + 2]);
                float vb = 0.125f * (xrB[2 * o] + xrB[2 * o + 3])
                         + 0.375f * (xrB[2 * o + 1] + xrB[2 * o + 2]);
                v_s[((buf * 16 + cha) * 4 + o) * VS + lane] = va;
                v_s[((buf * 16 + chb) * 4 + o) * VS + lane] = vb;
            }
        }
    };

    prefetch(0);
    vwrite(0);
    prefetch(16);
    __syncthreads();

    for (int t = 0; t < 8; t++) {
        const int buf = t & 1;
        if (t < 7) {
            vwrite(buf ^ 1);                    // chunk t+1 -> other buffer
            if (t < 6) prefetch((t + 2) * 16);  // issue loads for chunk t+2
        }
        // ---- GEMM over the 16 channels of chunk t ----
        #pragma unroll
        for (int cc = 0; cc < 16; cc++) {
            const float* vp = &v_s[((buf * 16 + cc) * 4 + ohl) * VS + 2 * owl];
            float v0 = vp[0], v1 = vp[1], v2 = vp[2], v3 = vp[3];
            float y = 0.125f * (v0 + v3) + 0.375f * (v1 + v2);
            const float* wrow = w + ((t * 16 + cc) << 8) + oc0;  // wave-uniform -> s_load
            #pragma unroll
            for (int i = 0; i < 32; i++)
                acc[i] = fmaf(wrow[i], y, acc[i]);
        }
        __syncthreads();   // v-writes(t+1) visible; GEMM(t) reads drained
    }

    // ---- epilogue: oc = oc0+i, oh = oh0+ohl, ow = ow0+owl ----
    {
        size_t base = (((size_t)n * 256 + oc0) * 256 + (size_t)(oh0 + ohl)) * 256
                      + ow0 + owl;
        #pragma unroll
        for (int i = 0; i < 32; i++)
            out[base + (size_t)i * 65536] = acc[i];
    }
}

extern "C" void kernel_launch(void* const* d_in, const int* in_sizes, int n_in,
                              void* d_out, int out_size, void* d_ws, size_t ws_size,
                              hipStream_t stream) {
    const float* x = (const float*)d_in[0];
    const float* w = (const float*)d_in[1];
    float* out = (float*)d_out;

    dim3 grid(16, 64, 4);   // ow-tiles(16 wide), oh-tiles(4 tall), n
    dim3 block(512);
    hipLaunchKernelGGL(fused_downconv_v11, grid, block, 0, stream, x, w, out);
}